// Round 1
// baseline (11520.498 us; speedup 1.0000x reference)
//
#include <hip/hip_runtime.h>
#include <hip/hip_bf16.h>

typedef __attribute__((ext_vector_type(8))) short short8;
typedef __attribute__((ext_vector_type(4))) float f32x4;

static constexpr int VOC = 50257;

__device__ inline unsigned short f2bf(float f){
  unsigned u = __float_as_uint(f);
  unsigned r = (u + 0x7fffu + ((u >> 16) & 1u)) >> 16;
  return (unsigned short)r;
}

// ---------------- embedding ----------------
__global__ __launch_bounds__(192) void embed_kernel(const int* __restrict__ idx,
    const float* __restrict__ wte, const float* __restrict__ wpe, float* __restrict__ x){
  int row = blockIdx.x;              // b*1024+t
  int t = row & 1023;
  int id = idx[row];
  const float* w = wte + (size_t)id * 768;
  const float* p = wpe + (size_t)t * 768;
  float* o = x + (size_t)row * 768;
  int c = threadIdx.x * 4;
  float4 a = *(const float4*)(w + c);
  float4 b = *(const float4*)(p + c);
  float4 r; r.x = a.x + b.x; r.y = a.y + b.y; r.z = a.z + b.z; r.w = a.w + b.w;
  *(float4*)(o + c) = r;
}

// ---------------- layernorm (fp32 in, bf16 out) ----------------
__global__ __launch_bounds__(256) void ln_kernel(const float* __restrict__ x,
    const float* __restrict__ w, const float* __restrict__ b,
    unsigned short* __restrict__ out){
  __shared__ float red[4];
  int row = blockIdx.x, tid = threadIdx.x;
  const float* xr = x + (size_t)row * 768;
  float v0 = xr[tid], v1 = xr[tid + 256], v2 = xr[tid + 512];
  float s = v0 + v1 + v2;
  #pragma unroll
  for (int o = 32; o; o >>= 1) s += __shfl_xor(s, o, 64);
  if ((tid & 63) == 0) red[tid >> 6] = s;
  __syncthreads();
  s = red[0] + red[1] + red[2] + red[3];
  float mu = s * (1.f / 768.f);
  float d0 = v0 - mu, d1 = v1 - mu, d2 = v2 - mu;
  float q = d0 * d0 + d1 * d1 + d2 * d2;
  __syncthreads();
  #pragma unroll
  for (int o = 32; o; o >>= 1) q += __shfl_xor(q, o, 64);
  if ((tid & 63) == 0) red[tid >> 6] = q;
  __syncthreads();
  q = red[0] + red[1] + red[2] + red[3];
  float rstd = rsqrtf(q * (1.f / 768.f) + 1e-5f);
  unsigned short* orow = out + (size_t)row * 768;
  orow[tid]       = f2bf(d0 * rstd * w[tid]       + b[tid]);
  orow[tid + 256] = f2bf(d1 * rstd * w[tid + 256] + b[tid + 256]);
  orow[tid + 512] = f2bf(d2 * rstd * w[tid + 512] + b[tid + 512]);
}

// ---------------- transpose + cvt: W[K,N] f32 -> WT[N,K] bf16 ----------------
__global__ void transpose_cvt(const float* __restrict__ W, unsigned short* __restrict__ WT,
                              int K, int N){
  __shared__ float t[32][33];
  int n0 = blockIdx.x * 32, k0 = blockIdx.y * 32;
  int tx = threadIdx.x, ty = threadIdx.y; // (32,8)
  #pragma unroll
  for (int i = 0; i < 4; i++)
    t[ty + i * 8][tx] = W[(size_t)(k0 + ty + i * 8) * N + n0 + tx];
  __syncthreads();
  #pragma unroll
  for (int i = 0; i < 4; i++)
    WT[(size_t)(n0 + ty + i * 8) * K + k0 + tx] = f2bf(t[tx][ty + i * 8]);
}

// ---------------- elementwise f32 -> bf16 ----------------
__global__ void cvt_bf16_kernel(const float* __restrict__ src, unsigned short* __restrict__ dst, int n4){
  int i = blockIdx.x * blockDim.x + threadIdx.x;
  int stride = gridDim.x * blockDim.x;
  for (; i < n4; i += stride){
    float4 v = *(const float4*)(src + (size_t)i * 4);
    size_t o = (size_t)i * 4;
    dst[o + 0] = f2bf(v.x); dst[o + 1] = f2bf(v.y);
    dst[o + 2] = f2bf(v.z); dst[o + 3] = f2bf(v.w);
  }
}

// ---------------- GEMM: C[M,N] = A[M,K](bf16) * B^T (B given as [N,K] bf16) ----------------
// 128x128 tile, BK=64, 4 waves (2x2 of 64x64), mfma_f32_16x16x32_bf16,
// global_load_lds(16B) with both-sides XOR swizzle (chunk ^= row&7).
__global__ __launch_bounds__(256) void gemm_bt(
    const unsigned short* __restrict__ A,
    const unsigned short* __restrict__ Bm,
    const float* __restrict__ bias,
    const float* __restrict__ resid,
    float* __restrict__ outF,
    unsigned short* __restrict__ outB,
    int M, int N, int K, int actGelu)
{
  __shared__ unsigned short tA[128 * 64];
  __shared__ unsigned short tB[128 * 64];
  const int lane = threadIdx.x & 63;
  const int wid  = threadIdx.x >> 6;
  const int wr = wid >> 1, wc = wid & 1;
  const int lr = lane & 15, lk = lane >> 4;
  const int brow = blockIdx.y * 128;
  const int bcol = blockIdx.x * 128;
  const int nValid = N - bcol;

  f32x4 acc[4][4];
  #pragma unroll
  for (int m = 0; m < 4; m++)
    #pragma unroll
    for (int n = 0; n < 4; n++)
      acc[m][n] = (f32x4){0.f, 0.f, 0.f, 0.f};

  for (int k0 = 0; k0 < K; k0 += 64){
    #pragma unroll
    for (int i = 0; i < 4; i++){
      int p = (i * 4 + wid) * 64 + lane;      // 16B chunk id 0..1023
      int r = p >> 3, c = p & 7;
      int cs = c ^ (r & 7);                    // inverse-swizzled source chunk
      const unsigned short* g = A + (size_t)(brow + r) * K + k0 + cs * 8;
      __builtin_amdgcn_global_load_lds(
        (const __attribute__((address_space(1))) unsigned int*)g,
        (__attribute__((address_space(3))) unsigned int*)(tA + (size_t)(i * 4 + wid) * 64 * 8),
        16, 0, 0);
    }
    #pragma unroll
    for (int i = 0; i < 4; i++){
      int p = (i * 4 + wid) * 64 + lane;
      int r = p >> 3, c = p & 7;
      int cs = c ^ (r & 7);
      int rr = r < nValid ? r : (nValid - 1);  // clamp for N tail (lm_head)
      const unsigned short* g = Bm + (size_t)(bcol + rr) * K + k0 + cs * 8;
      __builtin_amdgcn_global_load_lds(
        (const __attribute__((address_space(1))) unsigned int*)g,
        (__attribute__((address_space(3))) unsigned int*)(tB + (size_t)(i * 4 + wid) * 64 * 8),
        16, 0, 0);
    }
    __syncthreads();
    #pragma unroll
    for (int kk = 0; kk < 2; kk++){
      short8 av[4], bv[4];
      #pragma unroll
      for (int m = 0; m < 4; m++){
        int R = wr * 64 + m * 16 + lr;
        int c = kk * 4 + lk;
        av[m] = *(const short8*)&tA[R * 64 + ((c ^ (R & 7)) << 3)];
      }
      #pragma unroll
      for (int n = 0; n < 4; n++){
        int R = wc * 64 + n * 16 + lr;
        int c = kk * 4 + lk;
        bv[n] = *(const short8*)&tB[R * 64 + ((c ^ (R & 7)) << 3)];
      }
      #pragma unroll
      for (int m = 0; m < 4; m++)
        #pragma unroll
        for (int n = 0; n < 4; n++)
          acc[m][n] = __builtin_amdgcn_mfma_f32_16x16x32_bf16(av[m], bv[n], acc[m][n], 0, 0, 0);
    }
    __syncthreads();
  }

  // epilogue: C layout col=lane&15, row=(lane>>4)*4+reg
  #pragma unroll
  for (int m = 0; m < 4; m++){
    #pragma unroll
    for (int n = 0; n < 4; n++){
      int col = bcol + wc * 64 + n * 16 + lr;
      if (col < N){
        float bco = bias ? bias[col] : 0.f;
        #pragma unroll
        for (int j = 0; j < 4; j++){
          int row = brow + wr * 64 + m * 16 + lk * 4 + j;
          float v = acc[m][n][j] + bco;
          if (resid) v += resid[(size_t)row * N + col];
          if (actGelu){
            float x3 = v * v * v;
            v = 0.5f * v * (1.f + tanhf(0.79788456080286536f * (v + 0.044715f * x3)));
          }
          if (outF) outF[(size_t)row * N + col] = v;
          if (outB) outB[(size_t)row * N + col] = f2bf(v);
        }
      }
    }
  }
}

// ---------------- fused causal attention (fp32), one block per (qtile, h, b) ----------------
__global__ __launch_bounds__(256) void attn_kernel(const float* __restrict__ qkv,
                                                   unsigned short* __restrict__ y){
  __shared__ float Kl[64][68];
  __shared__ float Vl[64][68];
  __shared__ float Pl[64][68];
  const int qt = blockIdx.x, h = blockIdx.y, b = blockIdx.z;
  const int tid = threadIdx.x;
  const int r = tid >> 2, seg = tid & 3;
  const size_t rowBase = (size_t)(b * 1024 + qt * 64) * 2304;

  { // stage Q tile into Pl, then hoist own row to regs
    const float* src = qkv + rowBase + h * 64;
    #pragma unroll
    for (int i = 0; i < 4; i++){
      int f = i * 256 + tid;
      int rr = f >> 4, cc = (f & 15) << 2;
      *(float4*)&Pl[rr][cc] = *(const float4*)(src + (size_t)rr * 2304 + cc);
    }
  }
  __syncthreads();
  float4 qreg[16];
  #pragma unroll
  for (int d0 = 0; d0 < 16; d0++) qreg[d0] = *(const float4*)&Pl[r][d0 * 4];

  float4 o4[4];
  #pragma unroll
  for (int i = 0; i < 4; i++) o4[i] = make_float4(0.f, 0.f, 0.f, 0.f);
  float mold = -1e30f, lsum = 0.f;

  for (int kt = 0; kt <= qt; kt++){
    __syncthreads();
    const size_t kBase = (size_t)(b * 1024 + kt * 64) * 2304 + 768 + h * 64;
    const size_t vBase = kBase + 768;
    #pragma unroll
    for (int i = 0; i < 4; i++){
      int f = i * 256 + tid;
      int rr = f >> 4, cc = (f & 15) << 2;
      *(float4*)&Kl[rr][cc] = *(const float4*)(qkv + kBase + (size_t)rr * 2304 + cc);
      *(float4*)&Vl[rr][cc] = *(const float4*)(qkv + vBase + (size_t)rr * 2304 + cc);
    }
    __syncthreads();

    float s[16];
    const int jbase = seg * 16;
    #pragma unroll
    for (int jj = 0; jj < 16; jj++){
      int j = jbase + jj;
      float ax = 0.f, ay = 0.f, az = 0.f, aw = 0.f;
      #pragma unroll
      for (int d0 = 0; d0 < 16; d0++){
        float4 kv = *(const float4*)&Kl[j][d0 << 2];
        ax += qreg[d0].x * kv.x; ay += qreg[d0].y * kv.y;
        az += qreg[d0].z * kv.z; aw += qreg[d0].w * kv.w;
      }
      float sv = (ax + ay + az + aw) * 0.125f;
      if (kt == qt && j > r) sv = -1e30f;
      s[jj] = sv;
    }
    float mt = s[0];
    #pragma unroll
    for (int jj = 1; jj < 16; jj++) mt = fmaxf(mt, s[jj]);
    mt = fmaxf(mt, __shfl_xor(mt, 1, 64));
    mt = fmaxf(mt, __shfl_xor(mt, 2, 64));
    float mnew = fmaxf(mold, mt);
    float alpha = __expf(mold - mnew);
    float psum = 0.f;
    #pragma unroll
    for (int jj = 0; jj < 16; jj++){
      float p = __expf(s[jj] - mnew);
      Pl[r][jbase + jj] = p;
      psum += p;
    }
    lsum = lsum * alpha + psum;
    #pragma unroll
    for (int i = 0; i < 4; i++){
      o4[i].x *= alpha; o4[i].y *= alpha; o4[i].z *= alpha; o4[i].w *= alpha;
    }
    mold = mnew;
    #pragma unroll 8
    for (int j = 0; j < 64; j++){
      float pj = Pl[r][j];
      #pragma unroll
      for (int d0 = 0; d0 < 4; d0++){
        float4 vv = *(const float4*)&Vl[j][seg * 16 + d0 * 4];
        o4[d0].x += pj * vv.x; o4[d0].y += pj * vv.y;
        o4[d0].z += pj * vv.z; o4[d0].w += pj * vv.w;
      }
    }
  }
  lsum += __shfl_xor(lsum, 1, 64);
  lsum += __shfl_xor(lsum, 2, 64);
  float inv = 1.f / lsum;
  unsigned short* orow = y + (size_t)(b * 1024 + qt * 64 + r) * 768 + h * 64 + seg * 16;
  #pragma unroll
  for (int d0 = 0; d0 < 4; d0++){
    orow[d0 * 4 + 0] = f2bf(o4[d0].x * inv);
    orow[d0 * 4 + 1] = f2bf(o4[d0].y * inv);
    orow[d0 * 4 + 2] = f2bf(o4[d0].z * inv);
    orow[d0 * 4 + 3] = f2bf(o4[d0].w * inv);
  }
}

// ---------------- loss ----------------
__global__ __launch_bounds__(256) void loss_rows(const float* __restrict__ logits,
    const int* __restrict__ targets, float* __restrict__ nll){
  __shared__ float redM[4], redS[4];
  int row = blockIdx.x, tid = threadIdx.x;
  const float* lr = logits + (size_t)row * VOC;
  float m = -3.4e38f, s = 0.f;
  for (int i = tid; i < VOC; i += 256){
    float x = lr[i];
    float nm = fmaxf(m, x);
    s = s * __expf(m - nm) + __expf(x - nm);
    m = nm;
  }
  #pragma unroll
  for (int o = 32; o; o >>= 1){
    float m2 = __shfl_xor(m, o, 64);
    float s2 = __shfl_xor(s, o, 64);
    float nm = fmaxf(m, m2);
    s = s * __expf(m - nm) + s2 * __expf(m2 - nm);
    m = nm;
  }
  if ((tid & 63) == 0){ redM[tid >> 6] = m; redS[tid >> 6] = s; }
  __syncthreads();
  if (tid == 0){
    float M = fmaxf(fmaxf(redM[0], redM[1]), fmaxf(redM[2], redM[3]));
    float S = redS[0] * __expf(redM[0] - M) + redS[1] * __expf(redM[1] - M)
            + redS[2] * __expf(redM[2] - M) + redS[3] * __expf(redM[3] - M);
    float lse = M + logf(S);
    nll[row] = lse - lr[targets[row]];
  }
}

__global__ __launch_bounds__(256) void loss_final(const float* __restrict__ nll,
                                                  float* __restrict__ out){
  __shared__ float red[4];
  int tid = threadIdx.x;
  float s = 0.f;
  for (int i = tid; i < 4096; i += 256) s += nll[i];
  #pragma unroll
  for (int o = 32; o; o >>= 1) s += __shfl_xor(s, o, 64);
  if ((tid & 63) == 0) red[tid >> 6] = s;
  __syncthreads();
  if (tid == 0) out[0] = (red[0] + red[1] + red[2] + red[3]) * (1.f / 4096.f);
}

// ---------------- host ----------------
extern "C" void kernel_launch(void* const* d_in, const int* in_sizes, int n_in,
                              void* d_out, int out_size, void* d_ws, size_t ws_size,
                              hipStream_t stream){
  (void)in_sizes; (void)n_in; (void)out_size; (void)ws_size;
  const int*   idx     = (const int*)d_in[0];
  const int*   targets = (const int*)d_in[1];
  const float* wte     = (const float*)d_in[2];
  const float* wpe     = (const float*)d_in[3];
  const float* ln1w    = (const float*)d_in[4];
  const float* ln1b    = (const float*)d_in[5];
  const float* qkvw    = (const float*)d_in[6];
  const float* qkvb    = (const float*)d_in[7];
  const float* apw     = (const float*)d_in[8];
  const float* apb     = (const float*)d_in[9];
  const float* ln2w    = (const float*)d_in[10];
  const float* ln2b    = (const float*)d_in[11];
  const float* fcw     = (const float*)d_in[12];
  const float* fcb     = (const float*)d_in[13];
  const float* mpw     = (const float*)d_in[14];
  const float* mpb     = (const float*)d_in[15];
  const float* lnfw    = (const float*)d_in[16];
  const float* lnfb    = (const float*)d_in[17];

  char* ws = (char*)d_ws;
  size_t off = 0;
  auto alloc = [&](size_t bytes){
    void* p = ws + off; off += (bytes + 255) & ~(size_t)255; return p;
  };
  float* x               = (float*)alloc((size_t)4096 * 768 * 4);
  float* qkv             = (float*)alloc((size_t)4096 * 2304 * 4);
  unsigned short* hbf    = (unsigned short*)alloc((size_t)4096 * 768 * 2);
  unsigned short* ybf    = (unsigned short*)alloc((size_t)4096 * 768 * 2);
  unsigned short* gbf    = (unsigned short*)alloc((size_t)4096 * 3072 * 2);
  unsigned short* wT     = (unsigned short*)alloc((size_t)3072 * 768 * 2);
  unsigned short* wtebf  = (unsigned short*)alloc((size_t)VOC * 768 * 2);
  float* nll             = (float*)alloc((size_t)4096 * 4);

  float* logits  = (float*)d_out;
  float* lossOut = logits + (size_t)4096 * VOC;

  cvt_bf16_kernel<<<2048, 256, 0, stream>>>(wte, wtebf, (VOC * 768) / 4);
  embed_kernel<<<4096, 192, 0, stream>>>(idx, wte, wpe, x);

  for (int l = 0; l < 12; l++){
    ln_kernel<<<4096, 256, 0, stream>>>(x, ln1w + l * 768, ln1b + l * 768, hbf);
    transpose_cvt<<<dim3(2304 / 32, 768 / 32), dim3(32, 8), 0, stream>>>(
        qkvw + (size_t)l * 768 * 2304, wT, 768, 2304);
    gemm_bt<<<dim3(2304 / 128, 4096 / 128), 256, 0, stream>>>(
        hbf, wT, qkvb + l * 2304, nullptr, qkv, nullptr, 4096, 2304, 768, 0);
    attn_kernel<<<dim3(16, 12, 4), 256, 0, stream>>>(qkv, ybf);
    transpose_cvt<<<dim3(768 / 32, 768 / 32), dim3(32, 8), 0, stream>>>(
        apw + (size_t)l * 768 * 768, wT, 768, 768);
    gemm_bt<<<dim3(768 / 128, 4096 / 128), 256, 0, stream>>>(
        ybf, wT, apb + l * 768, x, x, nullptr, 4096, 768, 768, 0);
    ln_kernel<<<4096, 256, 0, stream>>>(x, ln2w + l * 768, ln2b + l * 768, hbf);
    transpose_cvt<<<dim3(3072 / 32, 768 / 32), dim3(32, 8), 0, stream>>>(
        fcw + (size_t)l * 768 * 3072, wT, 768, 3072);
    gemm_bt<<<dim3(3072 / 128, 4096 / 128), 256, 0, stream>>>(
        hbf, wT, fcb + l * 3072, nullptr, nullptr, gbf, 4096, 3072, 768, 1);
    transpose_cvt<<<dim3(768 / 32, 3072 / 32), dim3(32, 8), 0, stream>>>(
        mpw + (size_t)l * 3072 * 768, wT, 3072, 768);
    gemm_bt<<<dim3(768 / 128, 4096 / 128), 256, 0, stream>>>(
        gbf, wT, mpb + l * 768, x, x, nullptr, 4096, 768, 3072, 0);
  }
  ln_kernel<<<4096, 256, 0, stream>>>(x, lnfw, lnfb, hbf);
  gemm_bt<<<dim3((VOC + 127) / 128, 4096 / 128), 256, 0, stream>>>(
      hbf, wtebf, nullptr, nullptr, logits, nullptr, 4096, VOC, 768, 0);
  loss_rows<<<4096, 256, 0, stream>>>(logits, targets, nll);
  loss_final<<<1, 256, 0, stream>>>(nll, lossOut);
}

// Round 2
// 4060.236 us; speedup vs baseline: 2.8374x; 2.8374x over previous
//
#include <hip/hip_runtime.h>
#include <hip/hip_bf16.h>

typedef __attribute__((ext_vector_type(8))) short short8;
typedef __attribute__((ext_vector_type(4))) float f32x4;

static constexpr int VOC = 50257;

__device__ inline unsigned short f2bf(float f){
  unsigned u = __float_as_uint(f);
  unsigned r = (u + 0x7fffu + ((u >> 16) & 1u)) >> 16;
  return (unsigned short)r;
}

// ---------------- embedding ----------------
__global__ __launch_bounds__(192) void embed_kernel(const int* __restrict__ idx,
    const float* __restrict__ wte, const float* __restrict__ wpe, float* __restrict__ x){
  int row = blockIdx.x;              // b*1024+t
  int t = row & 1023;
  int id = idx[row];
  const float* w = wte + (size_t)id * 768;
  const float* p = wpe + (size_t)t * 768;
  float* o = x + (size_t)row * 768;
  int c = threadIdx.x * 4;
  float4 a = *(const float4*)(w + c);
  float4 b = *(const float4*)(p + c);
  float4 r; r.x = a.x + b.x; r.y = a.y + b.y; r.z = a.z + b.z; r.w = a.w + b.w;
  *(float4*)(o + c) = r;
}

// ---------------- layernorm (fp32 in, bf16 out) ----------------
__global__ __launch_bounds__(256) void ln_kernel(const float* __restrict__ x,
    const float* __restrict__ w, const float* __restrict__ b,
    unsigned short* __restrict__ out){
  __shared__ float red[4];
  int row = blockIdx.x, tid = threadIdx.x;
  const float* xr = x + (size_t)row * 768;
  float v0 = xr[tid], v1 = xr[tid + 256], v2 = xr[tid + 512];
  float s = v0 + v1 + v2;
  #pragma unroll
  for (int o = 32; o; o >>= 1) s += __shfl_xor(s, o, 64);
  if ((tid & 63) == 0) red[tid >> 6] = s;
  __syncthreads();
  s = red[0] + red[1] + red[2] + red[3];
  float mu = s * (1.f / 768.f);
  float d0 = v0 - mu, d1 = v1 - mu, d2 = v2 - mu;
  float q = d0 * d0 + d1 * d1 + d2 * d2;
  __syncthreads();
  #pragma unroll
  for (int o = 32; o; o >>= 1) q += __shfl_xor(q, o, 64);
  if ((tid & 63) == 0) red[tid >> 6] = q;
  __syncthreads();
  q = red[0] + red[1] + red[2] + red[3];
  float rstd = rsqrtf(q * (1.f / 768.f) + 1e-5f);
  unsigned short* orow = out + (size_t)row * 768;
  orow[tid]       = f2bf(d0 * rstd * w[tid]       + b[tid]);
  orow[tid + 256] = f2bf(d1 * rstd * w[tid + 256] + b[tid + 256]);
  orow[tid + 512] = f2bf(d2 * rstd * w[tid + 512] + b[tid + 512]);
}

// ---------------- transpose + cvt: W[K,N] f32 -> WT[N,K] bf16 ----------------
__global__ void transpose_cvt(const float* __restrict__ W, unsigned short* __restrict__ WT,
                              int K, int N){
  __shared__ float t[32][33];
  int n0 = blockIdx.x * 32, k0 = blockIdx.y * 32;
  int tx = threadIdx.x, ty = threadIdx.y; // (32,8)
  #pragma unroll
  for (int i = 0; i < 4; i++)
    t[ty + i * 8][tx] = W[(size_t)(k0 + ty + i * 8) * N + n0 + tx];
  __syncthreads();
  #pragma unroll
  for (int i = 0; i < 4; i++)
    WT[(size_t)(n0 + ty + i * 8) * K + k0 + tx] = f2bf(t[tx][ty + i * 8]);
}

// ---------------- elementwise f32 -> bf16 ----------------
__global__ void cvt_bf16_kernel(const float* __restrict__ src, unsigned short* __restrict__ dst, int n4){
  int i = blockIdx.x * blockDim.x + threadIdx.x;
  int stride = gridDim.x * blockDim.x;
  for (; i < n4; i += stride){
    float4 v = *(const float4*)(src + (size_t)i * 4);
    size_t o = (size_t)i * 4;
    dst[o + 0] = f2bf(v.x); dst[o + 1] = f2bf(v.y);
    dst[o + 2] = f2bf(v.z); dst[o + 3] = f2bf(v.w);
  }
}

// ---------------- GEMM: C[M,N] = A[M,K](bf16) * B^T (B given as [N,K] bf16) ----------------
__global__ __launch_bounds__(256) void gemm_bt(
    const unsigned short* __restrict__ A,
    const unsigned short* __restrict__ Bm,
    const float* __restrict__ bias,
    const float* __restrict__ resid,
    float* __restrict__ outF,
    unsigned short* __restrict__ outB,
    int M, int N, int K, int actGelu)
{
  __shared__ unsigned short tA[128 * 64];
  __shared__ unsigned short tB[128 * 64];
  const int lane = threadIdx.x & 63;
  const int wid  = threadIdx.x >> 6;
  const int wr = wid >> 1, wc = wid & 1;
  const int lr = lane & 15, lk = lane >> 4;
  const int brow = blockIdx.y * 128;
  const int bcol = blockIdx.x * 128;
  const int nValid = N - bcol;

  f32x4 acc[4][4];
  #pragma unroll
  for (int m = 0; m < 4; m++)
    #pragma unroll
    for (int n = 0; n < 4; n++)
      acc[m][n] = (f32x4){0.f, 0.f, 0.f, 0.f};

  for (int k0 = 0; k0 < K; k0 += 64){
    #pragma unroll
    for (int i = 0; i < 4; i++){
      int p = (i * 4 + wid) * 64 + lane;      // 16B chunk id 0..1023
      int r = p >> 3, c = p & 7;
      int cs = c ^ (r & 7);                    // inverse-swizzled source chunk
      const unsigned short* g = A + (size_t)(brow + r) * K + k0 + cs * 8;
      __builtin_amdgcn_global_load_lds(
        (const __attribute__((address_space(1))) unsigned int*)g,
        (__attribute__((address_space(3))) unsigned int*)(tA + (size_t)(i * 4 + wid) * 64 * 8),
        16, 0, 0);
    }
    #pragma unroll
    for (int i = 0; i < 4; i++){
      int p = (i * 4 + wid) * 64 + lane;
      int r = p >> 3, c = p & 7;
      int cs = c ^ (r & 7);
      int rr = r < nValid ? r : (nValid - 1);  // clamp for N tail (lm_head)
      const unsigned short* g = Bm + (size_t)(bcol + rr) * K + k0 + cs * 8;
      __builtin_amdgcn_global_load_lds(
        (const __attribute__((address_space(1))) unsigned int*)g,
        (__attribute__((address_space(3))) unsigned int*)(tB + (size_t)(i * 4 + wid) * 64 * 8),
        16, 0, 0);
    }
    __syncthreads();
    #pragma unroll
    for (int kk = 0; kk < 2; kk++){
      short8 av[4], bv[4];
      #pragma unroll
      for (int m = 0; m < 4; m++){
        int R = wr * 64 + m * 16 + lr;
        int c = kk * 4 + lk;
        av[m] = *(const short8*)&tA[R * 64 + ((c ^ (R & 7)) << 3)];
      }
      #pragma unroll
      for (int n = 0; n < 4; n++){
        int R = wc * 64 + n * 16 + lr;
        int c = kk * 4 + lk;
        bv[n] = *(const short8*)&tB[R * 64 + ((c ^ (R & 7)) << 3)];
      }
      #pragma unroll
      for (int m = 0; m < 4; m++)
        #pragma unroll
        for (int n = 0; n < 4; n++)
          acc[m][n] = __builtin_amdgcn_mfma_f32_16x16x32_bf16(av[m], bv[n], acc[m][n], 0, 0, 0);
    }
    __syncthreads();
  }

  #pragma unroll
  for (int m = 0; m < 4; m++){
    #pragma unroll
    for (int n = 0; n < 4; n++){
      int col = bcol + wc * 64 + n * 16 + lr;
      if (col < N){
        float bco = bias ? bias[col] : 0.f;
        #pragma unroll
        for (int j = 0; j < 4; j++){
          int row = brow + wr * 64 + m * 16 + lk * 4 + j;
          float v = acc[m][n][j] + bco;
          if (resid) v += resid[(size_t)row * N + col];
          if (actGelu){
            float x3 = v * v * v;
            v = 0.5f * v * (1.f + tanhf(0.79788456080286536f * (v + 0.044715f * x3)));
          }
          if (outF) outF[(size_t)row * N + col] = v;
          if (outB) outB[(size_t)row * N + col] = f2bf(v);
        }
      }
    }
  }
}

// ---------------- repack qkv f32 -> Q,K [BH,T,64] bf16, VT [BH,64,T] bf16 ----------------
__global__ __launch_bounds__(256) void repack_qkv(const float* __restrict__ qkv,
    unsigned short* __restrict__ Qb, unsigned short* __restrict__ Kb,
    unsigned short* __restrict__ VT){
  __shared__ float tl[32][33];
  int tx = threadIdx.x, ty = threadIdx.y;   // (32,8)
  int t0 = blockIdx.x * 32;
  int h = blockIdx.y >> 1, dt = (blockIdx.y & 1) * 32;
  int b = blockIdx.z;
  size_t bh = (size_t)(b * 12 + h);
  #pragma unroll
  for (int i = 0; i < 4; i++){
    int t = t0 + ty + i * 8;
    const float* src = qkv + (size_t)(b * 1024 + t) * 2304 + h * 64 + dt + tx;
    float qv = src[0], kv = src[768], vv = src[1536];
    size_t o = (bh * 1024 + t) * 64 + dt + tx;
    Qb[o] = f2bf(qv); Kb[o] = f2bf(kv);
    tl[ty + i * 8][tx] = vv;
  }
  __syncthreads();
  #pragma unroll
  for (int i = 0; i < 4; i++)
    VT[(bh * 64 + dt + ty + i * 8) * 1024 + t0 + tx] = f2bf(tl[tx][ty + i * 8]);
}

// ---------------- MFMA flash attention ----------------
// block = 4 waves; wave w owns 16 q-rows of a 64-row q-tile. KVBLK=64.
// K/VT tiles in LDS with XOR swizzle (both-sides, via global_load_lds);
// P re-shaped through per-wave LDS tile (stride 72 -> 16B aligned, ~2-way).
__global__ __launch_bounds__(256) void attn_mfma(
    const unsigned short* __restrict__ Qb,   // [BH,1024,64]
    const unsigned short* __restrict__ Kb,   // [BH,1024,64]
    const unsigned short* __restrict__ VT,   // [BH,64,1024]
    unsigned short* __restrict__ y)          // [B*T,768]
{
  __shared__ unsigned short Kl[64 * 64];
  __shared__ unsigned short Vl[64 * 64];
  __shared__ unsigned short Pl[4][16 * 72];
  const int xq = blockIdx.x;
  const int qt = (xq & 1) ? (xq >> 1) : (15 - (xq >> 1)); // interleave heavy/light
  const int h = blockIdx.y, b = blockIdx.z;
  const size_t bh = (size_t)(b * 12 + h);
  const int lane = threadIdx.x & 63;
  const int w = threadIdx.x >> 6;
  const int lr = lane & 15, lk = lane >> 4;

  // Q fragments in registers
  short8 aq[2];
  {
    const unsigned short* qrow = Qb + ((bh * 1024) + qt * 64 + w * 16 + lr) * 64;
    aq[0] = *(const short8*)&qrow[lk * 8];
    aq[1] = *(const short8*)&qrow[32 + lk * 8];
  }

  f32x4 o[4];
  #pragma unroll
  for (int n = 0; n < 4; n++) o[n] = (f32x4){0.f, 0.f, 0.f, 0.f};
  float mold[4] = {-1e30f, -1e30f, -1e30f, -1e30f};
  float lsum[4] = {0.f, 0.f, 0.f, 0.f};

  for (int kt = 0; kt <= qt; kt++){
    // stage K tile [64 keys][64 d] and VT tile [64 d][64 keys], swizzled
    #pragma unroll
    for (int i = 0; i < 2; i++){
      int p = (i * 4 + w) * 64 + lane;
      int r = p >> 3, c = p & 7;
      int cs = c ^ (r & 7);
      const unsigned short* gk = Kb + (bh * 1024 + (size_t)kt * 64 + r) * 64 + cs * 8;
      __builtin_amdgcn_global_load_lds(
        (const __attribute__((address_space(1))) unsigned int*)gk,
        (__attribute__((address_space(3))) unsigned int*)(Kl + (size_t)(i * 4 + w) * 64 * 8),
        16, 0, 0);
      const unsigned short* gv = VT + (bh * 64 + r) * 1024 + (size_t)kt * 64 + cs * 8;
      __builtin_amdgcn_global_load_lds(
        (const __attribute__((address_space(1))) unsigned int*)gv,
        (__attribute__((address_space(3))) unsigned int*)(Vl + (size_t)(i * 4 + w) * 64 * 8),
        16, 0, 0);
    }
    __syncthreads();

    // S = Q K^T  (rows = q, cols = key)
    f32x4 s[4];
    #pragma unroll
    for (int n = 0; n < 4; n++) s[n] = (f32x4){0.f, 0.f, 0.f, 0.f};
    #pragma unroll
    for (int ck = 0; ck < 2; ck++){
      #pragma unroll
      for (int n = 0; n < 4; n++){
        int R = n * 16 + lr, c = ck * 4 + lk;
        short8 bv = *(const short8*)&Kl[R * 64 + ((c ^ (R & 7)) << 3)];
        s[n] = __builtin_amdgcn_mfma_f32_16x16x32_bf16(aq[ck], bv, s[n], 0, 0, 0);
      }
    }
    // scale + causal mask
    #pragma unroll
    for (int n = 0; n < 4; n++)
      #pragma unroll
      for (int j = 0; j < 4; j++){
        float v = s[n][j] * 0.125f;
        if (kt == qt && (n * 16 + lr) > (w * 16 + lk * 4 + j)) v = -1e30f;
        s[n][j] = v;
      }
    // online softmax (row = q = lk*4+j; reduce over n in-lane, lr cross-lane)
    float mt[4];
    #pragma unroll
    for (int j = 0; j < 4; j++)
      mt[j] = fmaxf(fmaxf(s[0][j], s[1][j]), fmaxf(s[2][j], s[3][j]));
    #pragma unroll
    for (int msk = 1; msk < 16; msk <<= 1)
      #pragma unroll
      for (int j = 0; j < 4; j++)
        mt[j] = fmaxf(mt[j], __shfl_xor(mt[j], msk, 64));
    #pragma unroll
    for (int j = 0; j < 4; j++){
      float mn = fmaxf(mold[j], mt[j]);
      float a = __expf(mold[j] - mn);
      mold[j] = mn;
      lsum[j] *= a;
      #pragma unroll
      for (int n = 0; n < 4; n++){
        float p = __expf(s[n][j] - mn);
        s[n][j] = p;
        lsum[j] += p;
      }
      #pragma unroll
      for (int n2 = 0; n2 < 4; n2++) o[n2][j] *= a;
    }
    // P -> per-wave LDS (bf16), stride 72
    #pragma unroll
    for (int n = 0; n < 4; n++)
      #pragma unroll
      for (int j = 0; j < 4; j++)
        Pl[w][(lk * 4 + j) * 72 + n * 16 + lr] = f2bf(s[n][j]);
    __syncthreads();
    // O += P * V   (A = P [16q x 64k], B = VT [64d x 64k])
    #pragma unroll
    for (int ck = 0; ck < 2; ck++){
      short8 pa = *(const short8*)&Pl[w][lr * 72 + ck * 32 + lk * 8];
      #pragma unroll
      for (int n2 = 0; n2 < 4; n2++){
        int R = n2 * 16 + lr, c = ck * 4 + lk;
        short8 vv = *(const short8*)&Vl[R * 64 + ((c ^ (R & 7)) << 3)];
        o[n2] = __builtin_amdgcn_mfma_f32_16x16x32_bf16(pa, vv, o[n2], 0, 0, 0);
      }
    }
    __syncthreads();
  }

  #pragma unroll
  for (int msk = 1; msk < 16; msk <<= 1)
    #pragma unroll
    for (int j = 0; j < 4; j++)
      lsum[j] += __shfl_xor(lsum[j], msk, 64);
  float inv[4];
  #pragma unroll
  for (int j = 0; j < 4; j++) inv[j] = 1.f / lsum[j];

  #pragma unroll
  for (int n2 = 0; n2 < 4; n2++)
    #pragma unroll
    for (int j = 0; j < 4; j++){
      size_t row = (size_t)(b * 1024 + qt * 64 + w * 16 + lk * 4 + j);
      y[row * 768 + h * 64 + n2 * 16 + lr] = f2bf(o[n2][j] * inv[j]);
    }
}

// ---------------- loss ----------------
__global__ __launch_bounds__(256) void loss_rows(const float* __restrict__ logits,
    const int* __restrict__ targets, float* __restrict__ nll){
  __shared__ float redM[4], redS[4];
  int row = blockIdx.x, tid = threadIdx.x;
  const float* lr = logits + (size_t)row * VOC;
  float m = -3.4e38f, s = 0.f;
  for (int i = tid; i < VOC; i += 256){
    float x = lr[i];
    float nm = fmaxf(m, x);
    s = s * __expf(m - nm) + __expf(x - nm);
    m = nm;
  }
  #pragma unroll
  for (int o = 32; o; o >>= 1){
    float m2 = __shfl_xor(m, o, 64);
    float s2 = __shfl_xor(s, o, 64);
    float nm = fmaxf(m, m2);
    s = s * __expf(m - nm) + s2 * __expf(m2 - nm);
    m = nm;
  }
  if ((tid & 63) == 0){ redM[tid >> 6] = m; redS[tid >> 6] = s; }
  __syncthreads();
  if (tid == 0){
    float M = fmaxf(fmaxf(redM[0], redM[1]), fmaxf(redM[2], redM[3]));
    float S = redS[0] * __expf(redM[0] - M) + redS[1] * __expf(redM[1] - M)
            + redS[2] * __expf(redM[2] - M) + redS[3] * __expf(redM[3] - M);
    float lse = M + logf(S);
    nll[row] = lse - lr[targets[row]];
  }
}

__global__ __launch_bounds__(256) void loss_final(const float* __restrict__ nll,
                                                  float* __restrict__ out){
  __shared__ float red[4];
  int tid = threadIdx.x;
  float s = 0.f;
  for (int i = tid; i < 4096; i += 256) s += nll[i];
  #pragma unroll
  for (int o = 32; o; o >>= 1) s += __shfl_xor(s, o, 64);
  if ((tid & 63) == 0) red[tid >> 6] = s;
  __syncthreads();
  if (tid == 0) out[0] = (red[0] + red[1] + red[2] + red[3]) * (1.f / 4096.f);
}

// ---------------- host ----------------
extern "C" void kernel_launch(void* const* d_in, const int* in_sizes, int n_in,
                              void* d_out, int out_size, void* d_ws, size_t ws_size,
                              hipStream_t stream){
  (void)in_sizes; (void)n_in; (void)out_size; (void)ws_size;
  const int*   idx     = (const int*)d_in[0];
  const int*   targets = (const int*)d_in[1];
  const float* wte     = (const float*)d_in[2];
  const float* wpe     = (const float*)d_in[3];
  const float* ln1w    = (const float*)d_in[4];
  const float* ln1b    = (const float*)d_in[5];
  const float* qkvw    = (const float*)d_in[6];
  const float* qkvb    = (const float*)d_in[7];
  const float* apw     = (const float*)d_in[8];
  const float* apb     = (const float*)d_in[9];
  const float* ln2w    = (const float*)d_in[10];
  const float* ln2b    = (const float*)d_in[11];
  const float* fcw     = (const float*)d_in[12];
  const float* fcb     = (const float*)d_in[13];
  const float* mpw     = (const float*)d_in[14];
  const float* mpb     = (const float*)d_in[15];
  const float* lnfw    = (const float*)d_in[16];
  const float* lnfb    = (const float*)d_in[17];

  char* ws = (char*)d_ws;
  size_t off = 0;
  auto alloc = [&](size_t bytes){
    void* p = ws + off; off += (bytes + 255) & ~(size_t)255; return p;
  };
  float* x               = (float*)alloc((size_t)4096 * 768 * 4);
  float* qkv             = (float*)alloc((size_t)4096 * 2304 * 4);
  unsigned short* hbf    = (unsigned short*)alloc((size_t)4096 * 768 * 2);
  unsigned short* ybf    = (unsigned short*)alloc((size_t)4096 * 768 * 2);
  unsigned short* gbf    = (unsigned short*)alloc((size_t)4096 * 3072 * 2);
  unsigned short* wT     = (unsigned short*)alloc((size_t)3072 * 768 * 2);
  unsigned short* wtebf  = (unsigned short*)alloc((size_t)VOC * 768 * 2);
  unsigned short* qb     = (unsigned short*)alloc((size_t)48 * 1024 * 64 * 2);
  unsigned short* kbf    = (unsigned short*)alloc((size_t)48 * 1024 * 64 * 2);
  unsigned short* vtb    = (unsigned short*)alloc((size_t)48 * 1024 * 64 * 2);
  float* nll             = (float*)alloc((size_t)4096 * 4);

  float* logits  = (float*)d_out;
  float* lossOut = logits + (size_t)4096 * VOC;

  cvt_bf16_kernel<<<2048, 256, 0, stream>>>(wte, wtebf, (VOC * 768) / 4);
  embed_kernel<<<4096, 192, 0, stream>>>(idx, wte, wpe, x);

  for (int l = 0; l < 12; l++){
    ln_kernel<<<4096, 256, 0, stream>>>(x, ln1w + l * 768, ln1b + l * 768, hbf);
    transpose_cvt<<<dim3(2304 / 32, 768 / 32), dim3(32, 8), 0, stream>>>(
        qkvw + (size_t)l * 768 * 2304, wT, 768, 2304);
    gemm_bt<<<dim3(2304 / 128, 4096 / 128), 256, 0, stream>>>(
        hbf, wT, qkvb + l * 2304, nullptr, qkv, nullptr, 4096, 2304, 768, 0);
    repack_qkv<<<dim3(32, 24, 4), dim3(32, 8), 0, stream>>>(qkv, qb, kbf, vtb);
    attn_mfma<<<dim3(16, 12, 4), 256, 0, stream>>>(qb, kbf, vtb, ybf);
    transpose_cvt<<<dim3(768 / 32, 768 / 32), dim3(32, 8), 0, stream>>>(
        apw + (size_t)l * 768 * 768, wT, 768, 768);
    gemm_bt<<<dim3(768 / 128, 4096 / 128), 256, 0, stream>>>(
        ybf, wT, apb + l * 768, x, x, nullptr, 4096, 768, 768, 0);
    ln_kernel<<<4096, 256, 0, stream>>>(x, ln2w + l * 768, ln2b + l * 768, hbf);
    transpose_cvt<<<dim3(3072 / 32, 768 / 32), dim3(32, 8), 0, stream>>>(
        fcw + (size_t)l * 768 * 3072, wT, 768, 3072);
    gemm_bt<<<dim3(3072 / 128, 4096 / 128), 256, 0, stream>>>(
        hbf, wT, fcb + l * 3072, nullptr, nullptr, gbf, 4096, 3072, 768, 1);
    transpose_cvt<<<dim3(768 / 32, 3072 / 32), dim3(32, 8), 0, stream>>>(
        mpw + (size_t)l * 3072 * 768, wT, 3072, 768);
    gemm_bt<<<dim3(768 / 128, 4096 / 128), 256, 0, stream>>>(
        gbf, wT, mpb + l * 768, x, x, nullptr, 4096, 768, 3072, 0);
  }
  ln_kernel<<<4096, 256, 0, stream>>>(x, lnfw, lnfb, hbf);
  gemm_bt<<<dim3((VOC + 127) / 128, 4096 / 128), 256, 0, stream>>>(
      hbf, wtebf, nullptr, nullptr, logits, nullptr, 4096, VOC, 768, 0);
  loss_rows<<<4096, 256, 0, stream>>>(logits, targets, nll);
  loss_final<<<1, 256, 0, stream>>>(nll, lossOut);
}

// Round 3
// 3910.135 us; speedup vs baseline: 2.9463x; 1.0384x over previous
//
#include <hip/hip_runtime.h>
#include <hip/hip_bf16.h>

typedef __attribute__((ext_vector_type(8))) short short8;
typedef __attribute__((ext_vector_type(4))) float f32x4;

static constexpr int VOC = 50257;

__device__ inline unsigned short f2bf(float f){
  unsigned u = __float_as_uint(f);
  unsigned r = (u + 0x7fffu + ((u >> 16) & 1u)) >> 16;
  return (unsigned short)r;
}

// ---------------- embedding ----------------
__global__ __launch_bounds__(192) void embed_kernel(const int* __restrict__ idx,
    const float* __restrict__ wte, const float* __restrict__ wpe, float* __restrict__ x){
  int row = blockIdx.x;              // b*1024+t
  int t = row & 1023;
  int id = idx[row];
  const float* w = wte + (size_t)id * 768;
  const float* p = wpe + (size_t)t * 768;
  float* o = x + (size_t)row * 768;
  int c = threadIdx.x * 4;
  float4 a = *(const float4*)(w + c);
  float4 b = *(const float4*)(p + c);
  float4 r; r.x = a.x + b.x; r.y = a.y + b.y; r.z = a.z + b.z; r.w = a.w + b.w;
  *(float4*)(o + c) = r;
}

// ---------------- layernorm (fp32 in, bf16 out) ----------------
__global__ __launch_bounds__(256) void ln_kernel(const float* __restrict__ x,
    const float* __restrict__ w, const float* __restrict__ b,
    unsigned short* __restrict__ out){
  __shared__ float red[4];
  int row = blockIdx.x, tid = threadIdx.x;
  const float* xr = x + (size_t)row * 768;
  float v0 = xr[tid], v1 = xr[tid + 256], v2 = xr[tid + 512];
  float s = v0 + v1 + v2;
  #pragma unroll
  for (int o = 32; o; o >>= 1) s += __shfl_xor(s, o, 64);
  if ((tid & 63) == 0) red[tid >> 6] = s;
  __syncthreads();
  s = red[0] + red[1] + red[2] + red[3];
  float mu = s * (1.f / 768.f);
  float d0 = v0 - mu, d1 = v1 - mu, d2 = v2 - mu;
  float q = d0 * d0 + d1 * d1 + d2 * d2;
  __syncthreads();
  #pragma unroll
  for (int o = 32; o; o >>= 1) q += __shfl_xor(q, o, 64);
  if ((tid & 63) == 0) red[tid >> 6] = q;
  __syncthreads();
  q = red[0] + red[1] + red[2] + red[3];
  float rstd = rsqrtf(q * (1.f / 768.f) + 1e-5f);
  unsigned short* orow = out + (size_t)row * 768;
  orow[tid]       = f2bf(d0 * rstd * w[tid]       + b[tid]);
  orow[tid + 256] = f2bf(d1 * rstd * w[tid + 256] + b[tid + 256]);
  orow[tid + 512] = f2bf(d2 * rstd * w[tid + 512] + b[tid + 512]);
}

// ---------------- transpose + cvt: W[K,N] f32 -> WT[N,K] bf16 ----------------
__global__ void transpose_cvt(const float* __restrict__ W, unsigned short* __restrict__ WT,
                              int K, int N){
  __shared__ float t[32][33];
  int n0 = blockIdx.x * 32, k0 = blockIdx.y * 32;
  int tx = threadIdx.x, ty = threadIdx.y; // (32,8)
  #pragma unroll
  for (int i = 0; i < 4; i++)
    t[ty + i * 8][tx] = W[(size_t)(k0 + ty + i * 8) * N + n0 + tx];
  __syncthreads();
  #pragma unroll
  for (int i = 0; i < 4; i++)
    WT[(size_t)(n0 + ty + i * 8) * K + k0 + tx] = f2bf(t[tx][ty + i * 8]);
}

// ---------------- elementwise f32 -> bf16 ----------------
__global__ void cvt_bf16_kernel(const float* __restrict__ src, unsigned short* __restrict__ dst, int n4){
  int i = blockIdx.x * blockDim.x + threadIdx.x;
  int stride = gridDim.x * blockDim.x;
  for (; i < n4; i += stride){
    float4 v = *(const float4*)(src + (size_t)i * 4);
    size_t o = (size_t)i * 4;
    dst[o + 0] = f2bf(v.x); dst[o + 1] = f2bf(v.y);
    dst[o + 2] = f2bf(v.z); dst[o + 3] = f2bf(v.w);
  }
}

// ---------------- GEMM: C[M,N] = A[M,K](bf16) * B^T (B given as [N,K] bf16) ----------------
// 128x128 tile, BK=64, 4 waves. XCD-bijective swizzle + M-fastest block decode
// for B-panel L2 reuse. Optional fused loss partials (lm_head):
// per (row, nblk): online (max, sum_exp) over the 128-col slice -> lossPart.
__global__ __launch_bounds__(256) void gemm_bt(
    const unsigned short* __restrict__ A,
    const unsigned short* __restrict__ Bm,
    const float* __restrict__ bias,
    const float* __restrict__ resid,
    float* __restrict__ outF,
    unsigned short* __restrict__ outB,
    float2* __restrict__ lossPart,
    int M, int N, int K, int actGelu)
{
  __shared__ unsigned short tA[128 * 64];
  __shared__ unsigned short tB[128 * 64];
  const int lane = threadIdx.x & 63;
  const int wid  = threadIdx.x >> 6;
  const int wr = wid >> 1, wc = wid & 1;
  const int lr = lane & 15, lk = lane >> 4;

  // XCD-bijective swizzle (m204) + M-fastest decode
  const int nbx = gridDim.x, nby = gridDim.y;
  const int nwg = nbx * nby;
  const int lin = blockIdx.y * nbx + blockIdx.x;   // dispatch order (x fastest)
  const int qq = nwg >> 3, rr8 = nwg & 7;
  const int xcd = lin & 7, loc = lin >> 3;
  const int wg = (xcd < rr8 ? xcd * (qq + 1) : rr8 * (qq + 1) + (xcd - rr8) * qq) + loc;
  const int mblk = wg % nby;
  const int nblk = wg / nby;
  const int brow = mblk * 128;
  const int bcol = nblk * 128;
  const int nValid = N - bcol;

  f32x4 acc[4][4];
  #pragma unroll
  for (int m = 0; m < 4; m++)
    #pragma unroll
    for (int n = 0; n < 4; n++)
      acc[m][n] = (f32x4){0.f, 0.f, 0.f, 0.f};

  for (int k0 = 0; k0 < K; k0 += 64){
    #pragma unroll
    for (int i = 0; i < 4; i++){
      int p = (i * 4 + wid) * 64 + lane;      // 16B chunk id 0..1023
      int r = p >> 3, c = p & 7;
      int cs = c ^ (r & 7);                    // inverse-swizzled source chunk
      const unsigned short* g = A + (size_t)(brow + r) * K + k0 + cs * 8;
      __builtin_amdgcn_global_load_lds(
        (const __attribute__((address_space(1))) unsigned int*)g,
        (__attribute__((address_space(3))) unsigned int*)(tA + (size_t)(i * 4 + wid) * 64 * 8),
        16, 0, 0);
    }
    #pragma unroll
    for (int i = 0; i < 4; i++){
      int p = (i * 4 + wid) * 64 + lane;
      int r = p >> 3, c = p & 7;
      int cs = c ^ (r & 7);
      int rc = r < nValid ? r : (nValid - 1);  // clamp for N tail (lm_head)
      const unsigned short* g = Bm + (size_t)(bcol + rc) * K + k0 + cs * 8;
      __builtin_amdgcn_global_load_lds(
        (const __attribute__((address_space(1))) unsigned int*)g,
        (__attribute__((address_space(3))) unsigned int*)(tB + (size_t)(i * 4 + wid) * 64 * 8),
        16, 0, 0);
    }
    __syncthreads();
    #pragma unroll
    for (int kk = 0; kk < 2; kk++){
      short8 av[4], bv[4];
      #pragma unroll
      for (int m = 0; m < 4; m++){
        int R = wr * 64 + m * 16 + lr;
        int c = kk * 4 + lk;
        av[m] = *(const short8*)&tA[R * 64 + ((c ^ (R & 7)) << 3)];
      }
      #pragma unroll
      for (int n = 0; n < 4; n++){
        int R = wc * 64 + n * 16 + lr;
        int c = kk * 4 + lk;
        bv[n] = *(const short8*)&tB[R * 64 + ((c ^ (R & 7)) << 3)];
      }
      #pragma unroll
      for (int m = 0; m < 4; m++)
        #pragma unroll
        for (int n = 0; n < 4; n++)
          acc[m][n] = __builtin_amdgcn_mfma_f32_16x16x32_bf16(av[m], bv[n], acc[m][n], 0, 0, 0);
    }
    __syncthreads();
  }

  // epilogue: C layout col=lane&15, row=(lane>>4)*4+reg
  #pragma unroll
  for (int m = 0; m < 4; m++){
    #pragma unroll
    for (int n = 0; n < 4; n++){
      int col = bcol + wc * 64 + n * 16 + lr;
      if (col < N){
        float bco = bias ? bias[col] : 0.f;
        #pragma unroll
        for (int j = 0; j < 4; j++){
          int row = brow + wr * 64 + m * 16 + lk * 4 + j;
          float v = acc[m][n][j] + bco;
          if (resid) v += resid[(size_t)row * N + col];
          if (actGelu){
            float x3 = v * v * v;
            v = 0.5f * v * (1.f + tanhf(0.79788456080286536f * (v + 0.044715f * x3)));
          }
          if (outF){
            float* p = &outF[(size_t)row * N + col];
            if (lossPart) __builtin_nontemporal_store(v, p);  // don't pollute L2
            else *p = v;
          }
          if (outB) outB[(size_t)row * N + col] = f2bf(v);
        }
      }
    }
  }

  // fused loss partials (lm_head only): per row, (max, sum_exp) over this 128-col slice
  if (lossPart){
    float* mred = (float*)tA;          // [2][2][64] reuse (safe: after final barrier)
    float* sred = mred + 256;
    #pragma unroll
    for (int m = 0; m < 4; m++){
      #pragma unroll
      for (int j = 0; j < 4; j++){
        float vv[4];
        float mx = -3.4e38f;
        #pragma unroll
        for (int n = 0; n < 4; n++){
          int col = bcol + wc * 64 + n * 16 + lr;
          vv[n] = (col < N) ? acc[m][n][j] : -3.4e38f;
          mx = fmaxf(mx, vv[n]);
        }
        #pragma unroll
        for (int msk = 1; msk < 16; msk <<= 1)
          mx = fmaxf(mx, __shfl_xor(mx, msk, 64));
        float sm = 0.f;
        #pragma unroll
        for (int n = 0; n < 4; n++){
          int col = bcol + wc * 64 + n * 16 + lr;
          if (col < N) sm += __expf(vv[n] - mx);
        }
        #pragma unroll
        for (int msk = 1; msk < 16; msk <<= 1)
          sm += __shfl_xor(sm, msk, 64);
        if (lr == 0){
          int rid = (wr * 2 + wc) * 64 + m * 16 + lk * 4 + j;
          mred[rid] = mx; sred[rid] = sm;
        }
      }
    }
    __syncthreads();
    if (threadIdx.x < 128){
      int wrsel = threadIdx.x >> 6, rowi = threadIdx.x & 63;
      float m0 = mred[(wrsel * 2 + 0) * 64 + rowi];
      float m1 = mred[(wrsel * 2 + 1) * 64 + rowi];
      float s0 = sred[(wrsel * 2 + 0) * 64 + rowi];
      float s1 = sred[(wrsel * 2 + 1) * 64 + rowi];
      float Mv = fmaxf(m0, m1);
      float Sv = (s0 > 0.f ? s0 * __expf(m0 - Mv) : 0.f)
               + (s1 > 0.f ? s1 * __expf(m1 - Mv) : 0.f);
      int grow = brow + wrsel * 64 + rowi;
      lossPart[(size_t)grow * nbx + nblk] = make_float2(Mv, Sv);
    }
  }
}

// ---------------- repack qkv f32 -> Q,K [BH,T,64] bf16, VT [BH,64,T] bf16 ----------------
__global__ __launch_bounds__(256) void repack_qkv(const float* __restrict__ qkv,
    unsigned short* __restrict__ Qb, unsigned short* __restrict__ Kb,
    unsigned short* __restrict__ VT){
  __shared__ float tl[32][33];
  int tx = threadIdx.x, ty = threadIdx.y;   // (32,8)
  int t0 = blockIdx.x * 32;
  int h = blockIdx.y >> 1, dt = (blockIdx.y & 1) * 32;
  int b = blockIdx.z;
  size_t bh = (size_t)(b * 12 + h);
  #pragma unroll
  for (int i = 0; i < 4; i++){
    int t = t0 + ty + i * 8;
    const float* src = qkv + (size_t)(b * 1024 + t) * 2304 + h * 64 + dt + tx;
    float qv = src[0], kv = src[768], vv = src[1536];
    size_t o = (bh * 1024 + t) * 64 + dt + tx;
    Qb[o] = f2bf(qv); Kb[o] = f2bf(kv);
    tl[ty + i * 8][tx] = vv;
  }
  __syncthreads();
  #pragma unroll
  for (int i = 0; i < 4; i++)
    VT[(bh * 64 + dt + ty + i * 8) * 1024 + t0 + tx] = f2bf(tl[tx][ty + i * 8]);
}

// ---------------- MFMA flash attention ----------------
__global__ __launch_bounds__(256) void attn_mfma(
    const unsigned short* __restrict__ Qb,   // [BH,1024,64]
    const unsigned short* __restrict__ Kb,   // [BH,1024,64]
    const unsigned short* __restrict__ VT,   // [BH,64,1024]
    unsigned short* __restrict__ y)          // [B*T,768]
{
  __shared__ unsigned short Kl[64 * 64];
  __shared__ unsigned short Vl[64 * 64];
  __shared__ unsigned short Pl[4][16 * 72];
  const int xq = blockIdx.x;
  const int qt = (xq & 1) ? (xq >> 1) : (15 - (xq >> 1)); // interleave heavy/light
  const int h = blockIdx.y, b = blockIdx.z;
  const size_t bh = (size_t)(b * 12 + h);
  const int lane = threadIdx.x & 63;
  const int w = threadIdx.x >> 6;
  const int lr = lane & 15, lk = lane >> 4;

  short8 aq[2];
  {
    const unsigned short* qrow = Qb + ((bh * 1024) + qt * 64 + w * 16 + lr) * 64;
    aq[0] = *(const short8*)&qrow[lk * 8];
    aq[1] = *(const short8*)&qrow[32 + lk * 8];
  }

  f32x4 o[4];
  #pragma unroll
  for (int n = 0; n < 4; n++) o[n] = (f32x4){0.f, 0.f, 0.f, 0.f};
  float mold[4] = {-1e30f, -1e30f, -1e30f, -1e30f};
  float lsum[4] = {0.f, 0.f, 0.f, 0.f};

  for (int kt = 0; kt <= qt; kt++){
    #pragma unroll
    for (int i = 0; i < 2; i++){
      int p = (i * 4 + w) * 64 + lane;
      int r = p >> 3, c = p & 7;
      int cs = c ^ (r & 7);
      const unsigned short* gk = Kb + (bh * 1024 + (size_t)kt * 64 + r) * 64 + cs * 8;
      __builtin_amdgcn_global_load_lds(
        (const __attribute__((address_space(1))) unsigned int*)gk,
        (__attribute__((address_space(3))) unsigned int*)(Kl + (size_t)(i * 4 + w) * 64 * 8),
        16, 0, 0);
      const unsigned short* gv = VT + (bh * 64 + r) * 1024 + (size_t)kt * 64 + cs * 8;
      __builtin_amdgcn_global_load_lds(
        (const __attribute__((address_space(1))) unsigned int*)gv,
        (__attribute__((address_space(3))) unsigned int*)(Vl + (size_t)(i * 4 + w) * 64 * 8),
        16, 0, 0);
    }
    __syncthreads();

    f32x4 s[4];
    #pragma unroll
    for (int n = 0; n < 4; n++) s[n] = (f32x4){0.f, 0.f, 0.f, 0.f};
    #pragma unroll
    for (int ck = 0; ck < 2; ck++){
      #pragma unroll
      for (int n = 0; n < 4; n++){
        int R = n * 16 + lr, c = ck * 4 + lk;
        short8 bv = *(const short8*)&Kl[R * 64 + ((c ^ (R & 7)) << 3)];
        s[n] = __builtin_amdgcn_mfma_f32_16x16x32_bf16(aq[ck], bv, s[n], 0, 0, 0);
      }
    }
    #pragma unroll
    for (int n = 0; n < 4; n++)
      #pragma unroll
      for (int j = 0; j < 4; j++){
        float v = s[n][j] * 0.125f;
        if (kt == qt && (n * 16 + lr) > (w * 16 + lk * 4 + j)) v = -1e30f;
        s[n][j] = v;
      }
    float mt[4];
    #pragma unroll
    for (int j = 0; j < 4; j++)
      mt[j] = fmaxf(fmaxf(s[0][j], s[1][j]), fmaxf(s[2][j], s[3][j]));
    #pragma unroll
    for (int msk = 1; msk < 16; msk <<= 1)
      #pragma unroll
      for (int j = 0; j < 4; j++)
        mt[j] = fmaxf(mt[j], __shfl_xor(mt[j], msk, 64));
    #pragma unroll
    for (int j = 0; j < 4; j++){
      float mn = fmaxf(mold[j], mt[j]);
      float a = __expf(mold[j] - mn);
      mold[j] = mn;
      lsum[j] *= a;
      #pragma unroll
      for (int n = 0; n < 4; n++){
        float p = __expf(s[n][j] - mn);
        s[n][j] = p;
        lsum[j] += p;
      }
      #pragma unroll
      for (int n2 = 0; n2 < 4; n2++) o[n2][j] *= a;
    }
    #pragma unroll
    for (int n = 0; n < 4; n++)
      #pragma unroll
      for (int j = 0; j < 4; j++)
        Pl[w][(lk * 4 + j) * 72 + n * 16 + lr] = f2bf(s[n][j]);
    __syncthreads();
    #pragma unroll
    for (int ck = 0; ck < 2; ck++){
      short8 pa = *(const short8*)&Pl[w][lr * 72 + ck * 32 + lk * 8];
      #pragma unroll
      for (int n2 = 0; n2 < 4; n2++){
        int R = n2 * 16 + lr, c = ck * 4 + lk;
        short8 vv = *(const short8*)&Vl[R * 64 + ((c ^ (R & 7)) << 3)];
        o[n2] = __builtin_amdgcn_mfma_f32_16x16x32_bf16(pa, vv, o[n2], 0, 0, 0);
      }
    }
    __syncthreads();
  }

  #pragma unroll
  for (int msk = 1; msk < 16; msk <<= 1)
    #pragma unroll
    for (int j = 0; j < 4; j++)
      lsum[j] += __shfl_xor(lsum[j], msk, 64);
  float inv[4];
  #pragma unroll
  for (int j = 0; j < 4; j++) inv[j] = 1.f / lsum[j];

  #pragma unroll
  for (int n2 = 0; n2 < 4; n2++)
    #pragma unroll
    for (int j = 0; j < 4; j++){
      size_t row = (size_t)(b * 1024 + qt * 64 + w * 16 + lk * 4 + j);
      y[row * 768 + h * 64 + n2 * 16 + lr] = f2bf(o[n2][j] * inv[j]);
    }
}

// ---------------- loss: combine per-block partials ----------------
__global__ __launch_bounds__(64) void loss_rows2(const float2* __restrict__ part,
    const float* __restrict__ logits, const int* __restrict__ targets,
    float* __restrict__ nll, int nPart){
  int row = blockIdx.x, lane = threadIdx.x;
  float m = -3.4e38f, s = 0.f;
  for (int i = lane; i < nPart; i += 64){
    float2 p = part[(size_t)row * nPart + i];
    if (p.y > 0.f){
      float nm = fmaxf(m, p.x);
      s = s * __expf(m - nm) + p.y * __expf(p.x - nm);
      m = nm;
    }
  }
  #pragma unroll
  for (int o = 32; o; o >>= 1){
    float m2 = __shfl_xor(m, o, 64);
    float s2 = __shfl_xor(s, o, 64);
    float nm = fmaxf(m, m2);
    s = s * __expf(m - nm) + s2 * __expf(m2 - nm);
    m = nm;
  }
  if (lane == 0)
    nll[row] = m + logf(s) - logits[(size_t)row * VOC + targets[row]];
}

__global__ __launch_bounds__(256) void loss_final(const float* __restrict__ nll,
                                                  float* __restrict__ out){
  __shared__ float red[4];
  int tid = threadIdx.x;
  float s = 0.f;
  for (int i = tid; i < 4096; i += 256) s += nll[i];
  #pragma unroll
  for (int o = 32; o; o >>= 1) s += __shfl_xor(s, o, 64);
  if ((tid & 63) == 0) red[tid >> 6] = s;
  __syncthreads();
  if (tid == 0) out[0] = (red[0] + red[1] + red[2] + red[3]) * (1.f / 4096.f);
}

// ---------------- host ----------------
extern "C" void kernel_launch(void* const* d_in, const int* in_sizes, int n_in,
                              void* d_out, int out_size, void* d_ws, size_t ws_size,
                              hipStream_t stream){
  (void)in_sizes; (void)n_in; (void)out_size; (void)ws_size;
  const int*   idx     = (const int*)d_in[0];
  const int*   targets = (const int*)d_in[1];
  const float* wte     = (const float*)d_in[2];
  const float* wpe     = (const float*)d_in[3];
  const float* ln1w    = (const float*)d_in[4];
  const float* ln1b    = (const float*)d_in[5];
  const float* qkvw    = (const float*)d_in[6];
  const float* qkvb    = (const float*)d_in[7];
  const float* apw     = (const float*)d_in[8];
  const float* apb     = (const float*)d_in[9];
  const float* ln2w    = (const float*)d_in[10];
  const float* ln2b    = (const float*)d_in[11];
  const float* fcw     = (const float*)d_in[12];
  const float* fcb     = (const float*)d_in[13];
  const float* mpw     = (const float*)d_in[14];
  const float* mpb     = (const float*)d_in[15];
  const float* lnfw    = (const float*)d_in[16];
  const float* lnfb    = (const float*)d_in[17];

  char* ws = (char*)d_ws;
  size_t off = 0;
  auto alloc = [&](size_t bytes){
    void* p = ws + off; off += (bytes + 255) & ~(size_t)255; return p;
  };
  float* x               = (float*)alloc((size_t)4096 * 768 * 4);
  float* qkv             = (float*)alloc((size_t)4096 * 2304 * 4);
  unsigned short* hbf    = (unsigned short*)alloc((size_t)4096 * 768 * 2);
  unsigned short* ybf    = (unsigned short*)alloc((size_t)4096 * 768 * 2);
  unsigned short* gbf    = (unsigned short*)alloc((size_t)4096 * 3072 * 2);
  unsigned short* wT     = (unsigned short*)alloc((size_t)3072 * 768 * 2);
  unsigned short* wtebf  = (unsigned short*)alloc((size_t)VOC * 768 * 2);
  unsigned short* qb     = (unsigned short*)alloc((size_t)48 * 1024 * 64 * 2);
  unsigned short* kbf    = (unsigned short*)alloc((size_t)48 * 1024 * 64 * 2);
  unsigned short* vtb    = (unsigned short*)alloc((size_t)48 * 1024 * 64 * 2);
  float2* lossPart       = (float2*)alloc((size_t)4096 * 393 * 8);
  float* nll             = (float*)alloc((size_t)4096 * 4);

  float* logits  = (float*)d_out;
  float* lossOut = logits + (size_t)4096 * VOC;

  cvt_bf16_kernel<<<2048, 256, 0, stream>>>(wte, wtebf, (VOC * 768) / 4);
  embed_kernel<<<4096, 192, 0, stream>>>(idx, wte, wpe, x);

  for (int l = 0; l < 12; l++){
    ln_kernel<<<4096, 256, 0, stream>>>(x, ln1w + l * 768, ln1b + l * 768, hbf);
    transpose_cvt<<<dim3(2304 / 32, 768 / 32), dim3(32, 8), 0, stream>>>(
        qkvw + (size_t)l * 768 * 2304, wT, 768, 2304);
    gemm_bt<<<dim3(2304 / 128, 4096 / 128), 256, 0, stream>>>(
        hbf, wT, qkvb + l * 2304, nullptr, qkv, nullptr, nullptr, 4096, 2304, 768, 0);
    repack_qkv<<<dim3(32, 24, 4), dim3(32, 8), 0, stream>>>(qkv, qb, kbf, vtb);
    attn_mfma<<<dim3(16, 12, 4), 256, 0, stream>>>(qb, kbf, vtb, ybf);
    transpose_cvt<<<dim3(768 / 32, 768 / 32), dim3(32, 8), 0, stream>>>(
        apw + (size_t)l * 768 * 768, wT, 768, 768);
    gemm_bt<<<dim3(768 / 128, 4096 / 128), 256, 0, stream>>>(
        ybf, wT, apb + l * 768, x, x, nullptr, nullptr, 4096, 768, 768, 0);
    ln_kernel<<<4096, 256, 0, stream>>>(x, ln2w + l * 768, ln2b + l * 768, hbf);
    transpose_cvt<<<dim3(3072 / 32, 768 / 32), dim3(32, 8), 0, stream>>>(
        fcw + (size_t)l * 768 * 3072, wT, 768, 3072);
    gemm_bt<<<dim3(3072 / 128, 4096 / 128), 256, 0, stream>>>(
        hbf, wT, fcb + l * 3072, nullptr, nullptr, gbf, nullptr, 4096, 3072, 768, 1);
    transpose_cvt<<<dim3(768 / 32, 3072 / 32), dim3(32, 8), 0, stream>>>(
        mpw + (size_t)l * 3072 * 768, wT, 3072, 768);
    gemm_bt<<<dim3(768 / 128, 4096 / 128), 256, 0, stream>>>(
        gbf, wT, mpb + l * 768, x, x, nullptr, nullptr, 4096, 768, 3072, 0);
  }
  ln_kernel<<<4096, 256, 0, stream>>>(x, lnfw, lnfb, hbf);
  gemm_bt<<<dim3((VOC + 127) / 128, 4096 / 128), 256, 0, stream>>>(
      hbf, wtebf, nullptr, nullptr, logits, nullptr, lossPart, 4096, VOC, 768, 0);
  loss_rows2<<<4096, 64, 0, stream>>>(lossPart, logits, targets, nll, (VOC + 127) / 128);
  loss_final<<<1, 256, 0, stream>>>(nll, lossOut);
}